// Round 9
// baseline (123.641 us; speedup 1.0000x reference)
//
#include <hip/hip_runtime.h>
#include <math.h>

// B=64, L=128, H=16, O=8
#define LQ   128
#define BQ   64
#define LL   (LQ*LQ)
#define H1   16
#define O2   8
#define TILE 16
#define NTHR 512
#define NWAVE 8
#define RPW  2           // output rows per wave in Phase D
#define REG  18          // f1 region (origin i0-1)
#define NPTS (REG*REG)   // 324
#define NPTS_PAD 336     // 21 groups * 16
#define NGRP 21
#define PCR  22          // pc region (origin i0-3)
#define PCN  (PCR*PCR)   // 484
#define LKR  23          // link region (origin i0-3)
#define LKN  (LKR*LKR)   // 529

typedef float f2 __attribute__((ext_vector_type(2)));
using bf8 = __attribute__((ext_vector_type(8))) short;     // 8 bf16 (4 VGPR)
using hf8 = __attribute__((ext_vector_type(8))) _Float16;  // 8 fp16 (4 VGPR)
using f4  = __attribute__((ext_vector_type(4))) float;     // MFMA C/D

__device__ __forceinline__ int wrapi(int v) { return v & (LQ - 1); }

// RNE pack: low16 = bf16(lo), high16 = bf16(hi)
__device__ __forceinline__ unsigned cvt_pk_bf16(float lo, float hi) {
    unsigned r;
    asm("v_cvt_pk_bf16_f32 %0, %1, %2" : "=v"(r) : "v"(lo), "v"(hi));
    return r;
}
// RTZ pack: low16 = fp16(lo), high16 = fp16(hi)
__device__ __forceinline__ unsigned cvt_pk_f16(float lo, float hi) {
    auto h2 = __builtin_amdgcn_cvt_pkrtz(lo, hi);
    unsigned r;
    __builtin_memcpy(&r, &h2, 4);
    return r;
}

// ws layout:
//   float2[0 .. BQ*LL)                     seed (8 MB)
//   uint4 [0 .. 256) at float ofs 2*BQ*LL  pre-packed MFMA A-fragments:
//     [0..64)    layer-1 W fragment per lane, fp16 (K15-31 zero)
//     [64..256)  layer-2 W fragments, 3 pairs x 64 lanes, bf16 RNE
#define WS_WF ((size_t)2 * BQ * LL)

// ---------------------------------------------------------------------------
__global__ __launch_bounds__(256)
void k_scan(const float* __restrict__ x,
            const float* __restrict__ c1, const float* __restrict__ fw1,
            const float* __restrict__ bw1,
            const float* __restrict__ c2, const float* __restrict__ fw2,
            const float* __restrict__ bw2, float* __restrict__ ws) {
    int blk = blockIdx.x;
    if (blk == BQ * 8) {
        int tid = threadIdx.x;
        uint4* wf = (uint4*)(ws + WS_WF);
        if (tid < 64) {
            // layer-1 A fragment (fp16): A[h][k], k=3q+c for k<15, else 0
            int kc = tid >> 4, h = tid & 15;
            unsigned dw[4];
            float v[8];
#pragma unroll
            for (int j = 0; j < 8; ++j) {
                int k = kc * 8 + j;
                float val = 0.f;
                if (k < 15) {
                    int q = k / 3, c = k - q * 3;
                    const float* src = (q == 0) ? c1 : (q == 1) ? fw1
                                     : (q == 2) ? bw1 : (q == 3) ? (fw1 + 48)
                                     : (bw1 + 48);
                    val = src[h * 3 + c];
                }
                v[j] = val;
            }
#pragma unroll
            for (int d = 0; d < 4; ++d) dw[d] = cvt_pk_f16(v[2*d], v[2*d+1]);
            uint4 u = {dw[0], dw[1], dw[2], dw[3]};
            wf[tid] = u;
        } else {
            // layer-2 A fragments (3 tap-pairs), per-lane as in Phase D (RNE)
            int idx = tid - 64;
            int pq = idx >> 6, lane = idx & 63;
            int kc = lane >> 4, h = lane & 15, half = kc >> 1;
            const float* wsrc = half
                ? ((pq == 0) ? fw2 : (pq == 1) ? (fw2 + O2 * H1) : (const float*)0)
                : ((pq == 0) ? c2  : (pq == 1) ? bw2 : (bw2 + O2 * H1));
            unsigned dw[4] = {0u, 0u, 0u, 0u};
            int wrow = half ? (h - 8) : h;
            bool valid = half ? (h >= 8 && wsrc != 0) : (h < 8);
            if (valid) {
                const float* wp2 = wsrc + wrow * H1 + (kc & 1) * 8;
#pragma unroll
                for (int d = 0; d < 4; ++d)
                    dw[d] = cvt_pk_bf16(wp2[2*d], wp2[2*d+1]);
            }
            uint4 u = {dw[0], dw[1], dw[2], dw[3]};
            wf[64 + idx] = u;
        }
        return;
    }
    int b = blk >> 3, rq = blk & 7;
    int l = threadIdx.x & 63, w = threadIdx.x >> 6;
    const float* x0 = x + (size_t)b * 4 * LL;
    const float* x1 = x0 + LL;

    float ur0 = x0[(2 * l) * LQ],     ui0 = x1[(2 * l) * LQ];
    float ur1 = x0[(2 * l + 1) * LQ], ui1 = x1[(2 * l + 1) * LQ];
    float pr = ur0 * ur1 - ui0 * ui1;
    float pi = ur0 * ui1 + ui0 * ur1;
    for (int d = 1; d < 64; d <<= 1) {
        float qr = __shfl_up(pr, d, 64);
        float qi = __shfl_up(pi, d, 64);
        if (l >= d) {
            float nr = qr * pr - qi * pi;
            float ni = qr * pi + qi * pr;
            pr = nr; pi = ni;
        }
    }
    float er = __shfl_up(pr, 1, 64);
    float ei = __shfl_up(pi, 1, 64);
    if (l == 0) { er = 1.f; ei = 0.f; }
    float e1r = er * ur0 - ei * ui0;
    float e1i = er * ui0 + ei * ur0;

    const float* yrp = x + (size_t)(b * 4 + 2) * LL;
    const float* yip = yrp + LL;
    float4* seed4 = (float4*)ws;

    for (int k = 0; k < 4; ++k) {
        int i = rq * 16 + w * 4 + k;
        float cxr = __shfl((i & 1) ? e1r : er, i >> 1, 64);
        float cxi = __shfl((i & 1) ? e1i : ei, i >> 1, 64);
        const float* yr = yrp + (size_t)i * LQ;
        const float* yi = yip + (size_t)i * LQ;
        float vr0 = yr[2 * l],     vi0 = yi[2 * l];
        float vr1 = yr[2 * l + 1], vi1 = yi[2 * l + 1];
        float sr = vr0 * vr1 - vi0 * vi1;
        float si = vr0 * vi1 + vi0 * vr1;
        for (int d = 1; d < 64; d <<= 1) {
            float qr = __shfl_up(sr, d, 64);
            float qi = __shfl_up(si, d, 64);
            if (l >= d) {
                float nr = qr * sr - qi * si;
                float ni = qr * si + qi * sr;
                sr = nr; si = ni;
            }
        }
        float gr = __shfl_up(sr, 1, 64);
        float gi = __shfl_up(si, 1, 64);
        if (l == 0) { gr = 1.f; gi = 0.f; }
        float s0r = cxr * gr - cxi * gi;
        float s0i = cxr * gi + cxi * gr;
        float s1r = s0r * vr0 - s0i * vi0;
        float s1i = s0r * vi0 + s0i * vr0;
        seed4[((size_t)b * LL + (size_t)i * LQ) / 2 + l] =
            make_float4(s0r, -s0i, s1r, -s1i);
    }
}

// ---------------------------------------------------------------------------
// s_f1 layout: per point P, 16 dwords in four 4-dword slots rotated by
// rot = (P>>1)&3:  dword(slot s, d) at 16*P + ((s+rot)&3)*4 + d.
// Feature phase (fp16, scaled by s=rcp(m), m=max|tap| in s_m[P]):
//   s0/1 = Fr d0-3/4-7 (K0-15, K15 pad), s2/3 = Fi.  A rows K15-31 are zero,
//   so kc>=2 lanes read the other plane as a finite dummy (exact 0 contrib).
// Output phase (C2 write, D read; bf16): s0/1 = out_r ch0-7/8-15, s2/3 = out_i.
__global__ __launch_bounds__(NTHR, 8)
void k_main(const float* __restrict__ x,
            const float* __restrict__ b1, const float* __restrict__ b2,
            const float* __restrict__ ro, const float* __restrict__ rob,
            const float* __restrict__ ws, float* __restrict__ out) {
    __shared__ __align__(16) unsigned s_f1[NPTS_PAD * 16];   // 21504 B
    __shared__ f2 s_ux[LKN];                 // 4232 B
    __shared__ f2 s_uy[LKN];                 // 4232 B
    __shared__ float s_pc[PCN];              // 1936 B
    __shared__ float s_m[NPTS_PAD];          // 1344 B (total 33248 -> 4 blk/CU)
    int tid = threadIdx.x;
    int b = blockIdx.z, i0 = blockIdx.y * TILE, j0 = blockIdx.x * TILE;
    const float* x0 = x + (size_t)b * 4 * LL;
    const float* x1 = x0 + LL;
    const float* x2 = x0 + 2 * LL;
    const float* x3 = x0 + 3 * LL;
    const float2* seed = (const float2*)ws + (size_t)b * LL;
    const uint4* wf = (const uint4*)(ws + WS_WF);

    int lane = tid & 63, w = tid >> 6;
    int kc = lane >> 4, h = lane & 15, half = kc >> 1;

    // ---- Prefetch: C1 seed taps, issued at kernel entry, consumed after 2
    // barriers (latency hidden under Phases A+B). C1 is single-iteration
    // (336 < 512): addresses depend only on tid. Dead lanes clamp.
    int pp  = (tid < NPTS) ? tid : (NPTS - 1);
    int pri = pp / REG, prj = pp - pri * REG;
    const float2* srow0 = seed + wrapi(i0 - 1 + pri) * LQ;
    const float2* srowm = seed + wrapi(i0 - 2 + pri) * LQ;
    const float2* srowp = seed + wrapi(i0 + pri) * LQ;
    int pj0 = wrapi(j0 - 1 + prj), pjm = wrapi(j0 - 2 + prj), pjp = wrapi(j0 + prj);
    float2 SC  = srow0[pj0];
    float2 SXP = srowp[pj0];
    float2 SXM = srowm[pj0];
    float2 SYP = srow0[pjp];
    float2 SYM = srow0[pjm];

    // uniform zero-bias fast-path flags (exact: scale==1.0 when bias==0)
    bool z1 = true;
#pragma unroll
    for (int hh = 0; hh < H1; ++hh) z1 = z1 && (b1[hh] == 0.f);
    bool z2 = true;
#pragma unroll
    for (int oo = 0; oo < O2; ++oo) z2 = z2 && (b2[oo] == 0.f);

    // pre-packed A fragments (global, L2-hot: 4 KB shared by all blocks)
    hf8 a1;
    { uint4 u = wf[lane]; __builtin_memcpy(&a1, &u, 16); }
    bf8 afr[3];
#pragma unroll
    for (int pq = 0; pq < 3; ++pq) {
        uint4 u = wf[64 + pq * 64 + lane];
        __builtin_memcpy(&afr[pq], &u, 16);
    }

    // ---- Phase A: stage links (23x23, origin -3); seed stays in global ----
    for (int p = tid; p < LKN; p += NTHR) {
        int ri = p / LKR, rj = p - ri * LKR;
        int gi = wrapi(i0 - 3 + ri), gj = wrapi(j0 - 3 + rj);
        int idx = gi * LQ + gj;
        s_ux[p] = (f2){x0[idx], x1[idx]};
        s_uy[p] = (f2){x2[idx], x3[idx]};
    }
    __syncthreads();

    // ---- Phase B: pc on 22x22 (origin -3) via complex plaquette product ----
    for (int p = tid; p < PCN; p += NTHR) {
        int ri = p / PCR, rj = p - ri * PCR;
        int lb = ri * LKR + rj;
        f2 u1 = s_ux[lb];
        f2 u2 = s_uy[lb + LKR];
        f2 u3 = s_ux[lb + 1];
        f2 u4 = s_uy[lb];
        float ar = u1.x * u2.x - u1.y * u2.y, ai = u1.x * u2.y + u1.y * u2.x;
        float br = ar * u3.x + ai * u3.y,     bi = -ar * u3.y + ai * u3.x;
        float zr = br * u4.x + bi * u4.y,     zi = -br * u4.y + bi * u4.x;
        s_pc[p] = zr * __frsqrt_rn(fmaf(zr, zr, zi * zi) + 1e-30f);
    }
    __syncthreads();

    // ---- Phase C1: per-point 15-feature vector -> scaled fp16 -> s_f1 ----
    if (tid < NPTS_PAD) {
        int p = tid;
        int rot = (p >> 1) & 3;
        unsigned* dst = &s_f1[p * 16];
        if (p < NPTS) {
            int ri = pri, rj = prj;
            int lb = (ri + 2) * LKR + (rj + 2);
            int cb = (ri + 2) * PCR + (rj + 2);

            f2 lx = s_ux[lb], ly = s_uy[lb];
            f2 mx = s_ux[lb - LKR], my = s_uy[lb - 1];
            float tr[5], ti[5], tc[5], tv[5];
            tr[0] = SC.x;                          ti[0] = SC.y;
            tr[1] = lx.x * SXP.x - lx.y * SXP.y;   ti[1] = lx.x * SXP.y + lx.y * SXP.x;
            tr[2] = mx.x * SXM.x + mx.y * SXM.y;   ti[2] = mx.x * SXM.y - mx.y * SXM.x;
            tr[3] = ly.x * SYP.x - ly.y * SYP.y;   ti[3] = ly.x * SYP.y + ly.y * SYP.x;
            tr[4] = my.x * SYM.x + my.y * SYM.y;   ti[4] = my.x * SYM.y - my.y * SYM.x;

            // 13-point pc diamond
            float p00 = s_pc[cb];
            float pP0 = s_pc[cb + PCR],     pM0 = s_pc[cb - PCR];
            float p0P = s_pc[cb + 1],       p0M = s_pc[cb - 1];
            float pP20 = s_pc[cb + 2*PCR],  pM20 = s_pc[cb - 2*PCR];
            float p0P2 = s_pc[cb + 2],      p0M2 = s_pc[cb - 2];
            float pPP = s_pc[cb + PCR + 1], pPM = s_pc[cb + PCR - 1];
            float pMP = s_pc[cb - PCR + 1], pMM = s_pc[cb - PCR - 1];
            tc[0] = p00; tc[1] = pP0; tc[2] = pM0; tc[3] = p0P; tc[4] = p0M;
            tv[0] = (p00 + pP0 + pM0 + p0P + p0M) * 0.2f;
            tv[1] = (pP0 + pP20 + p00 + pPP + pPM) * 0.2f;
            tv[2] = (pM0 + p00 + pM20 + pMP + pMM) * 0.2f;
            tv[3] = (p0P + pPP + pMP + p0P2 + p00) * 0.2f;
            tv[4] = (p0M + pPM + pMM + p00 + p0M2) * 0.2f;

            // per-point scale: |F| <= m = max|tap| (|pc|,|pavg| <= 1)
            float m = 1e-30f;
#pragma unroll
            for (int q = 0; q < 5; ++q)
                m = fmaxf(m, fmaxf(fabsf(tr[q]), fabsf(ti[q])));
            float s = __frcp_rn(m);

            float Fr[16], Fi[16];
#pragma unroll
            for (int q = 0; q < 5; ++q) {
                float trq = tr[q] * s, tiq = ti[q] * s;
                Fr[3*q]   = trq;          Fi[3*q]   = tiq;
                Fr[3*q+1] = tc[q]*trq;    Fi[3*q+1] = tc[q]*tiq;
                Fr[3*q+2] = tv[q]*trq;    Fi[3*q+2] = tv[q]*tiq;
            }
            Fr[15] = 0.f; Fi[15] = 0.f;
            unsigned hr[8], hi_[8];
#pragma unroll
            for (int d = 0; d < 8; ++d) {
                hr[d]  = cvt_pk_f16(Fr[2*d], Fr[2*d+1]);
                hi_[d] = cvt_pk_f16(Fi[2*d], Fi[2*d+1]);
            }
            uint4 vs0 = {hr[0], hr[1], hr[2], hr[3]};
            uint4 vs1 = {hr[4], hr[5], hr[6], hr[7]};
            uint4 vs2 = {hi_[0], hi_[1], hi_[2], hi_[3]};
            uint4 vs3 = {hi_[4], hi_[5], hi_[6], hi_[7]};
            *(uint4*)&dst[((0 + rot) & 3) * 4] = vs0;
            *(uint4*)&dst[((1 + rot) & 3) * 4] = vs1;
            *(uint4*)&dst[((2 + rot) & 3) * 4] = vs2;
            *(uint4*)&dst[((3 + rot) & 3) * 4] = vs3;
            s_m[p] = m;
        } else {
            uint4 z = {0u, 0u, 0u, 0u};
#pragma unroll
            for (int sl = 0; sl < 4; ++sl) *(uint4*)&dst[sl * 4] = z;
            s_m[p] = 0.f;
        }
    }
    __syncthreads();

    // ---- Phase C2: layer1 fp16 MFMA per 16-point group, in-place out ----
    for (int g = w; g < NGRP; g += NWAVE) {
        int P = g * 16 + h;
        int rot = (P >> 1) & 3;
        unsigned* bb = &s_f1[P * 16];
        uint4 ur = *(const uint4*)&bb[((kc + rot) & 3) * 4];
        uint4 ui = *(const uint4*)&bb[(((kc ^ 2) + rot) & 3) * 4];
        hf8 br, bi;
        __builtin_memcpy(&br, &ur, 16);
        __builtin_memcpy(&bi, &ui, 16);
        f4 zc = {0.f, 0.f, 0.f, 0.f};
        f4 Dr = __builtin_amdgcn_mfma_f32_16x16x32_f16(a1, br, zc, 0, 0, 0);
        f4 Di = __builtin_amdgcn_mfma_f32_16x16x32_f16(a1, bi, zc, 0, 0, 0);
        if (P < NPTS) {
            float mm = s_m[P];
            Dr *= mm; Di *= mm;          // undo per-point feature scale
            if (!z1) {
#pragma unroll
                for (int r = 0; r < 4; ++r) {
                    float q2 = Dr[r]*Dr[r] + Di[r]*Di[r] + 1e-12f;
                    float sb = fmaxf(fmaf(b1[4*kc + r], __frsqrt_rn(q2), 1.f), 0.f);
                    Dr[r] *= sb; Di[r] *= sb;
                }
            }
            // lane holds out ch 4kc..4kc+3 of point P -> r dwords 2kc,2kc+1
            unsigned pr0 = cvt_pk_bf16(Dr[0], Dr[1]);
            unsigned pr1 = cvt_pk_bf16(Dr[2], Dr[3]);
            unsigned pi0 = cvt_pk_bf16(Di[0], Di[1]);
            unsigned pi1 = cvt_pk_bf16(Di[2], Di[3]);
            int base = P * 16 + ((kc & 1) << 1);
            int ar = base + ((((kc >> 1) + rot) & 3) << 2);
            int ai = base + ((((kc >> 1) + 2 + rot) & 3) << 2);
            *(uint2*)&s_f1[ar] = make_uint2(pr0, pr1);
            *(uint2*)&s_f1[ai] = make_uint2(pi0, pi1);
        }
    }
    __syncthreads();

    // ---- Phase D: layer2 via tap-paired MFMA + readout (bf16) ----
    float4 ro_lo = *(const float4*)ro;
    float4 ro_hi = *(const float4*)(ro + 4);
    float4 b2_lo = *(const float4*)b2;
    float4 b2_hi = *(const float4*)(b2 + 4);
    float4 zf4 = make_float4(0.f, 0.f, 0.f, 0.f);
    float4 rv = (kc == 0) ? ro_lo : ((kc == 1) ? ro_hi : zf4);
    float4 bv = (kc == 0) ? b2_lo : ((kc == 1) ? b2_hi : zf4);
    float rob0 = rob[0];

    // per-pair per-lane B tap offset (row-invariant; depends on half only)
    int dpl[3];
    dpl[0] = half ? REG : 0;
    dpl[1] = half ? 1 : -REG;
    dpl[2] = -1;

#pragma unroll
    for (int g = 0; g < RPW; ++g) {
        int row = w * RPW + g;
        int posc = (row + 1) * REG + (h + 1);
        int lb2 = (row + 3) * LKR + (h + 3);
        f2 lx = s_ux[lb2], ly = s_uy[lb2];
        f2 mx = s_ux[lb2 - LKR], my = s_uy[lb2 - 1];

        float Lr[3], Li[3];
        Lr[0] = half ? lx.x : 1.f;   Li[0] = half ? lx.y : 0.f;
        Lr[1] = half ? ly.x : mx.x;  Li[1] = half ? ly.y : -mx.y;
        Lr[2] = half ? 0.f : my.x;   Li[2] = half ? 0.f : -my.y;

        f2 a2r01 = {0.f, 0.f}, a2r23 = {0.f, 0.f};
        f2 a2i01 = {0.f, 0.f}, a2i23 = {0.f, 0.f};
#pragma unroll
        for (int pq = 0; pq < 3; ++pq) {
            int posc2 = posc + dpl[pq];
            int rot2 = (posc2 >> 1) & 3;
            int bbb = posc2 * 16;
            uint4 ur = *(const uint4*)&s_f1[bbb + ((((kc & 1) + rot2) & 3) << 2)];
            uint4 ui = *(const uint4*)&s_f1[bbb + ((((kc & 1) + 2 + rot2) & 3) << 2)];
            bf8 br, bi;
            __builtin_memcpy(&br, &ur, 16);
            __builtin_memcpy(&bi, &ui, 16);
            f4 zc = {0.f, 0.f, 0.f, 0.f};
            f4 sr = __builtin_amdgcn_mfma_f32_16x16x32_bf16(afr[pq], br, zc, 0, 0, 0);
            f4 si = __builtin_amdgcn_mfma_f32_16x16x32_bf16(afr[pq], bi, zc, 0, 0, 0);
            f2 sr01 = {sr[0], sr[1]}, sr23 = {sr[2], sr[3]};
            f2 si01 = {si[0], si[1]}, si23 = {si[2], si[3]};
            // a2r += Lr*sr - Li*si ; a2i += Lr*si + Li*sr
            a2r01 += Lr[pq] * sr01 - Li[pq] * si01;
            a2r23 += Lr[pq] * sr23 - Li[pq] * si23;
            a2i01 += Lr[pq] * si01 + Li[pq] * sr01;
            a2i23 += Lr[pq] * si23 + Li[pq] * sr23;
        }

        // fold highK-half rows (8-15, in quads 2/3) into lowK rows (quads 0/1)
        float ar_[4], ai_[4];
        ar_[0] = a2r01.x; ar_[1] = a2r01.y; ar_[2] = a2r23.x; ar_[3] = a2r23.y;
        ai_[0] = a2i01.x; ai_[1] = a2i01.y; ai_[2] = a2i23.x; ai_[3] = a2i23.y;
#pragma unroll
        for (int c = 0; c < 4; ++c) {
            ar_[c] += __shfl_xor(ar_[c], 32, 64);
            ai_[c] += __shfl_xor(ai_[c], 32, 64);
        }

        float q4[4];
#pragma unroll
        for (int c = 0; c < 4; ++c)
            q4[c] = ar_[c] * ar_[c] + ai_[c] * ai_[c];
        float res;
        if (z2) {
            res = rv.x * q4[0] + rv.y * q4[1] + rv.z * q4[2] + rv.w * q4[3];
        } else {
            float bvv[4] = {bv.x, bv.y, bv.z, bv.w};
            float rvv[4] = {rv.x, rv.y, rv.z, rv.w};
            res = 0.f;
#pragma unroll
            for (int r = 0; r < 4; ++r) {
                float qq = q4[r];
                float sb = fmaxf(fmaf(bvv[r], __frsqrt_rn(qq + 1e-12f), 1.f), 0.f);
                res = fmaf(rvv[r], sb * sb * qq, res);
            }
        }
        res += __shfl_xor(res, 16, 64);
        if (kc == 0)
            out[(size_t)b * LL + (size_t)(i0 + row) * LQ + (j0 + h)] = res + rob0;
    }
}

// ---------------------------------------------------------------------------
extern "C" void kernel_launch(void* const* d_in, const int* in_sizes, int n_in,
                              void* d_out, int out_size, void* d_ws, size_t ws_size,
                              hipStream_t stream) {
    const float* x   = (const float*)d_in[0];
    const float* c1  = (const float*)d_in[1];
    const float* fw1 = (const float*)d_in[2];
    const float* bw1 = (const float*)d_in[3];
    const float* b1  = (const float*)d_in[4];
    const float* c2  = (const float*)d_in[5];
    const float* fw2 = (const float*)d_in[6];
    const float* bw2 = (const float*)d_in[7];
    const float* b2  = (const float*)d_in[8];
    const float* ro  = (const float*)d_in[9];
    const float* rob = (const float*)d_in[10];
    float* out = (float*)d_out;
    float* ws  = (float*)d_ws;

    k_scan<<<BQ * 8 + 1, 256, 0, stream>>>(x, c1, fw1, bw1, c2, fw2, bw2, ws);
    dim3 grid(LQ / TILE, LQ / TILE, BQ);
    k_main<<<grid, NTHR, 0, stream>>>(x, b1, b2, ro, rob, ws, out);
}

// Round 10
// 123.499 us; speedup vs baseline: 1.0012x; 1.0012x over previous
//
#include <hip/hip_runtime.h>
#include <math.h>

// B=64, L=128, H=16, O=8
#define LQ   128
#define BQ   64
#define LL   (LQ*LQ)
#define H1   16
#define O2   8
#define TILE 16
#define NTHR 512
#define NWAVE 8
#define RPW  2           // output rows per wave in Phase D
#define REG  18          // f1 region (origin i0-1)
#define NPTS (REG*REG)   // 324
#define NPTS_PAD 336     // 21 groups * 16
#define NGRP 21
#define PCR  22          // pc region (origin i0-3)
#define PCN  (PCR*PCR)   // 484
#define LKR  23          // link region (origin i0-3)
#define LKN  (LKR*LKR)   // 529

typedef float f2 __attribute__((ext_vector_type(2)));
using bf8 = __attribute__((ext_vector_type(8))) short;     // 8 bf16 (4 VGPR)
using hf8 = __attribute__((ext_vector_type(8))) _Float16;  // 8 fp16 (4 VGPR)
using f4  = __attribute__((ext_vector_type(4))) float;     // MFMA C/D

__device__ __forceinline__ int wrapi(int v) { return v & (LQ - 1); }

// RNE pack: low16 = bf16(lo), high16 = bf16(hi)
__device__ __forceinline__ unsigned cvt_pk_bf16(float lo, float hi) {
    unsigned r;
    asm("v_cvt_pk_bf16_f32 %0, %1, %2" : "=v"(r) : "v"(lo), "v"(hi));
    return r;
}
// RTZ pack: low16 = fp16(lo), high16 = fp16(hi)
__device__ __forceinline__ unsigned cvt_pk_f16(float lo, float hi) {
    auto h2 = __builtin_amdgcn_cvt_pkrtz(lo, hi);
    unsigned r;
    __builtin_memcpy(&r, &h2, 4);
    return r;
}

// ws layout:
//   float2[0 .. BQ*LL)                     seed (8 MB)
//   uint4 [0 .. 256) at float ofs 2*BQ*LL  pre-packed MFMA A-fragments:
//     [0..64)    layer-1 W fragment per lane, fp16 (K15-31 zero)
//     [64..256)  layer-2 W fragments, 3 pairs x 64 lanes, bf16 RNE
#define WS_WF ((size_t)2 * BQ * LL)

// ---------------------------------------------------------------------------
__global__ __launch_bounds__(256)
void k_scan(const float* __restrict__ x,
            const float* __restrict__ c1, const float* __restrict__ fw1,
            const float* __restrict__ bw1,
            const float* __restrict__ c2, const float* __restrict__ fw2,
            const float* __restrict__ bw2, float* __restrict__ ws) {
    int blk = blockIdx.x;
    if (blk == BQ * 8) {
        int tid = threadIdx.x;
        uint4* wf = (uint4*)(ws + WS_WF);
        if (tid < 64) {
            // layer-1 A fragment (fp16): A[h][k], k=3q+c for k<15, else 0
            int kc = tid >> 4, h = tid & 15;
            unsigned dw[4];
            float v[8];
#pragma unroll
            for (int j = 0; j < 8; ++j) {
                int k = kc * 8 + j;
                float val = 0.f;
                if (k < 15) {
                    int q = k / 3, c = k - q * 3;
                    const float* src = (q == 0) ? c1 : (q == 1) ? fw1
                                     : (q == 2) ? bw1 : (q == 3) ? (fw1 + 48)
                                     : (bw1 + 48);
                    val = src[h * 3 + c];
                }
                v[j] = val;
            }
#pragma unroll
            for (int d = 0; d < 4; ++d) dw[d] = cvt_pk_f16(v[2*d], v[2*d+1]);
            uint4 u = {dw[0], dw[1], dw[2], dw[3]};
            wf[tid] = u;
        } else {
            // layer-2 A fragments (3 tap-pairs), per-lane as in Phase D (RNE)
            int idx = tid - 64;
            int pq = idx >> 6, lane = idx & 63;
            int kc = lane >> 4, h = lane & 15, half = kc >> 1;
            const float* wsrc = half
                ? ((pq == 0) ? fw2 : (pq == 1) ? (fw2 + O2 * H1) : (const float*)0)
                : ((pq == 0) ? c2  : (pq == 1) ? bw2 : (bw2 + O2 * H1));
            unsigned dw[4] = {0u, 0u, 0u, 0u};
            int wrow = half ? (h - 8) : h;
            bool valid = half ? (h >= 8 && wsrc != 0) : (h < 8);
            if (valid) {
                const float* wp2 = wsrc + wrow * H1 + (kc & 1) * 8;
#pragma unroll
                for (int d = 0; d < 4; ++d)
                    dw[d] = cvt_pk_bf16(wp2[2*d], wp2[2*d+1]);
            }
            uint4 u = {dw[0], dw[1], dw[2], dw[3]};
            wf[64 + idx] = u;
        }
        return;
    }
    int b = blk >> 3, rq = blk & 7;
    int l = threadIdx.x & 63, w = threadIdx.x >> 6;
    const float* x0 = x + (size_t)b * 4 * LL;
    const float* x1 = x0 + LL;

    float ur0 = x0[(2 * l) * LQ],     ui0 = x1[(2 * l) * LQ];
    float ur1 = x0[(2 * l + 1) * LQ], ui1 = x1[(2 * l + 1) * LQ];
    float pr = ur0 * ur1 - ui0 * ui1;
    float pi = ur0 * ui1 + ui0 * ur1;
    for (int d = 1; d < 64; d <<= 1) {
        float qr = __shfl_up(pr, d, 64);
        float qi = __shfl_up(pi, d, 64);
        if (l >= d) {
            float nr = qr * pr - qi * pi;
            float ni = qr * pi + qi * pr;
            pr = nr; pi = ni;
        }
    }
    float er = __shfl_up(pr, 1, 64);
    float ei = __shfl_up(pi, 1, 64);
    if (l == 0) { er = 1.f; ei = 0.f; }
    float e1r = er * ur0 - ei * ui0;
    float e1i = er * ui0 + ei * ur0;

    const float* yrp = x + (size_t)(b * 4 + 2) * LL;
    const float* yip = yrp + LL;
    float4* seed4 = (float4*)ws;

    for (int k = 0; k < 4; ++k) {
        int i = rq * 16 + w * 4 + k;
        float cxr = __shfl((i & 1) ? e1r : er, i >> 1, 64);
        float cxi = __shfl((i & 1) ? e1i : ei, i >> 1, 64);
        const float* yr = yrp + (size_t)i * LQ;
        const float* yi = yip + (size_t)i * LQ;
        float vr0 = yr[2 * l],     vi0 = yi[2 * l];
        float vr1 = yr[2 * l + 1], vi1 = yi[2 * l + 1];
        float sr = vr0 * vr1 - vi0 * vi1;
        float si = vr0 * vi1 + vi0 * vr1;
        for (int d = 1; d < 64; d <<= 1) {
            float qr = __shfl_up(sr, d, 64);
            float qi = __shfl_up(si, d, 64);
            if (l >= d) {
                float nr = qr * sr - qi * si;
                float ni = qr * si + qi * sr;
                sr = nr; si = ni;
            }
        }
        float gr = __shfl_up(sr, 1, 64);
        float gi = __shfl_up(si, 1, 64);
        if (l == 0) { gr = 1.f; gi = 0.f; }
        float s0r = cxr * gr - cxi * gi;
        float s0i = cxr * gi + cxi * gr;
        float s1r = s0r * vr0 - s0i * vi0;
        float s1i = s0r * vi0 + s0i * vr0;
        seed4[((size_t)b * LL + (size_t)i * LQ) / 2 + l] =
            make_float4(s0r, -s0i, s1r, -s1i);
    }
}

// ---------------------------------------------------------------------------
// s_f1 layout: per point P, 16 dwords in four 4-dword slots rotated by
// rot = (P>>1)&3:  dword(slot s, d) at 16*P + ((s+rot)&3)*4 + d.
// Feature phase (fp16, scaled by s=rcp(m), m=max|tap| in s_m[P]):
//   s0/1 = Fr d0-3/4-7 (K0-15, K15 pad), s2/3 = Fi.  A rows K15-31 are zero,
//   so kc>=2 lanes read the other plane as a finite dummy (exact 0 contrib).
// Output phase (C2 write, D read; bf16): s0/1 = out_r ch0-7/8-15, s2/3 = out_i.
__global__ __launch_bounds__(NTHR, 8)
void k_main(const float* __restrict__ x,
            const float* __restrict__ b1, const float* __restrict__ b2,
            const float* __restrict__ ro, const float* __restrict__ rob,
            const float* __restrict__ ws, float* __restrict__ out) {
    __shared__ __align__(16) unsigned s_f1[NPTS_PAD * 16];   // 21504 B
    __shared__ f2 s_ux[LKN];                 // 4232 B
    __shared__ f2 s_uy[LKN];                 // 4232 B
    __shared__ float s_pc[PCN];              // 1936 B
    __shared__ float s_m[NPTS_PAD];          // 1344 B (total 33248 -> 4 blk/CU)
    int tid = threadIdx.x;
    int b = blockIdx.z, i0 = blockIdx.y * TILE, j0 = blockIdx.x * TILE;
    const float* x0 = x + (size_t)b * 4 * LL;
    const float* x1 = x0 + LL;
    const float* x2 = x0 + 2 * LL;
    const float* x3 = x0 + 3 * LL;
    const float2* seed = (const float2*)ws + (size_t)b * LL;
    const uint4* wf = (const uint4*)(ws + WS_WF);

    int lane = tid & 63, w = tid >> 6;
    int kc = lane >> 4, h = lane & 15, half = kc >> 1;

    // uniform zero-bias fast-path flags (exact: scale==1.0 when bias==0)
    bool z1 = true;
#pragma unroll
    for (int hh = 0; hh < H1; ++hh) z1 = z1 && (b1[hh] == 0.f);
    bool z2 = true;
#pragma unroll
    for (int oo = 0; oo < O2; ++oo) z2 = z2 && (b2[oo] == 0.f);

    // pre-packed A fragments (global, L2-hot: 4 KB shared by all blocks)
    hf8 a1;
    { uint4 u = wf[lane]; __builtin_memcpy(&a1, &u, 16); }
    bf8 afr[3];
#pragma unroll
    for (int pq = 0; pq < 3; ++pq) {
        uint4 u = wf[64 + pq * 64 + lane];
        __builtin_memcpy(&afr[pq], &u, 16);
    }

    // ---- Phase A: stage links (23x23, origin -3); seed stays in global ----
    for (int p = tid; p < LKN; p += NTHR) {
        int ri = p / LKR, rj = p - ri * LKR;
        int gi = wrapi(i0 - 3 + ri), gj = wrapi(j0 - 3 + rj);
        int idx = gi * LQ + gj;
        s_ux[p] = (f2){x0[idx], x1[idx]};
        s_uy[p] = (f2){x2[idx], x3[idx]};
    }
    __syncthreads();

    // ---- Phase B: pc on 22x22 (origin -3) via complex plaquette product ----
    for (int p = tid; p < PCN; p += NTHR) {
        int ri = p / PCR, rj = p - ri * PCR;
        int lb = ri * LKR + rj;
        f2 u1 = s_ux[lb];
        f2 u2 = s_uy[lb + LKR];
        f2 u3 = s_ux[lb + 1];
        f2 u4 = s_uy[lb];
        float ar = u1.x * u2.x - u1.y * u2.y, ai = u1.x * u2.y + u1.y * u2.x;
        float br = ar * u3.x + ai * u3.y,     bi = -ar * u3.y + ai * u3.x;
        float zr = br * u4.x + bi * u4.y,     zi = -br * u4.y + bi * u4.x;
        s_pc[p] = zr * __frsqrt_rn(fmaf(zr, zr, zi * zi) + 1e-30f);
    }
    __syncthreads();

    // ---- Phase C1: per-point 15-feature vector -> scaled fp16 -> s_f1 ----
    for (int p = tid; p < NPTS_PAD; p += NTHR) {
        int rot = (p >> 1) & 3;
        unsigned* dst = &s_f1[p * 16];
        if (p < NPTS) {
            int ri = p / REG, rj = p - ri * REG;
            int lb = (ri + 2) * LKR + (rj + 2);
            int cb = (ri + 2) * PCR + (rj + 2);

            // seed taps from global (f1 point = global (i0-1+ri, j0-1+rj))
            int gi0 = wrapi(i0 - 1 + ri), gim = wrapi(i0 - 2 + ri), gip = wrapi(i0 + ri);
            int gj0 = wrapi(j0 - 1 + rj), gjm = wrapi(j0 - 2 + rj), gjp = wrapi(j0 + rj);
            float2 SC  = seed[gi0 * LQ + gj0];
            float2 SXP = seed[gip * LQ + gj0];
            float2 SXM = seed[gim * LQ + gj0];
            float2 SYP = seed[gi0 * LQ + gjp];
            float2 SYM = seed[gi0 * LQ + gjm];

            f2 lx = s_ux[lb], ly = s_uy[lb];
            f2 mx = s_ux[lb - LKR], my = s_uy[lb - 1];
            float tr[5], ti[5], tc[5], tv[5];
            tr[0] = SC.x;                          ti[0] = SC.y;
            tr[1] = lx.x * SXP.x - lx.y * SXP.y;   ti[1] = lx.x * SXP.y + lx.y * SXP.x;
            tr[2] = mx.x * SXM.x + mx.y * SXM.y;   ti[2] = mx.x * SXM.y - mx.y * SXM.x;
            tr[3] = ly.x * SYP.x - ly.y * SYP.y;   ti[3] = ly.x * SYP.y + ly.y * SYP.x;
            tr[4] = my.x * SYM.x + my.y * SYM.y;   ti[4] = my.x * SYM.y - my.y * SYM.x;

            // 13-point pc diamond
            float p00 = s_pc[cb];
            float pP0 = s_pc[cb + PCR],     pM0 = s_pc[cb - PCR];
            float p0P = s_pc[cb + 1],       p0M = s_pc[cb - 1];
            float pP20 = s_pc[cb + 2*PCR],  pM20 = s_pc[cb - 2*PCR];
            float p0P2 = s_pc[cb + 2],      p0M2 = s_pc[cb - 2];
            float pPP = s_pc[cb + PCR + 1], pPM = s_pc[cb + PCR - 1];
            float pMP = s_pc[cb - PCR + 1], pMM = s_pc[cb - PCR - 1];
            tc[0] = p00; tc[1] = pP0; tc[2] = pM0; tc[3] = p0P; tc[4] = p0M;
            tv[0] = (p00 + pP0 + pM0 + p0P + p0M) * 0.2f;
            tv[1] = (pP0 + pP20 + p00 + pPP + pPM) * 0.2f;
            tv[2] = (pM0 + p00 + pM20 + pMP + pMM) * 0.2f;
            tv[3] = (p0P + pPP + pMP + p0P2 + p00) * 0.2f;
            tv[4] = (p0M + pPM + pMM + p00 + p0M2) * 0.2f;

            // per-point scale: |F| <= m = max|tap| (|pc|,|pavg| <= 1)
            float m = 1e-30f;
#pragma unroll
            for (int q = 0; q < 5; ++q)
                m = fmaxf(m, fmaxf(fabsf(tr[q]), fabsf(ti[q])));
            float s = __frcp_rn(m);

            float Fr[16], Fi[16];
#pragma unroll
            for (int q = 0; q < 5; ++q) {
                float trq = tr[q] * s, tiq = ti[q] * s;
                Fr[3*q]   = trq;          Fi[3*q]   = tiq;
                Fr[3*q+1] = tc[q]*trq;    Fi[3*q+1] = tc[q]*tiq;
                Fr[3*q+2] = tv[q]*trq;    Fi[3*q+2] = tv[q]*tiq;
            }
            Fr[15] = 0.f; Fi[15] = 0.f;
            unsigned hr[8], hi_[8];
#pragma unroll
            for (int d = 0; d < 8; ++d) {
                hr[d]  = cvt_pk_f16(Fr[2*d], Fr[2*d+1]);
                hi_[d] = cvt_pk_f16(Fi[2*d], Fi[2*d+1]);
            }
            uint4 vs0 = {hr[0], hr[1], hr[2], hr[3]};
            uint4 vs1 = {hr[4], hr[5], hr[6], hr[7]};
            uint4 vs2 = {hi_[0], hi_[1], hi_[2], hi_[3]};
            uint4 vs3 = {hi_[4], hi_[5], hi_[6], hi_[7]};
            *(uint4*)&dst[((0 + rot) & 3) * 4] = vs0;
            *(uint4*)&dst[((1 + rot) & 3) * 4] = vs1;
            *(uint4*)&dst[((2 + rot) & 3) * 4] = vs2;
            *(uint4*)&dst[((3 + rot) & 3) * 4] = vs3;
            s_m[p] = m;
        } else {
            uint4 z = {0u, 0u, 0u, 0u};
#pragma unroll
            for (int sl = 0; sl < 4; ++sl) *(uint4*)&dst[sl * 4] = z;
            s_m[p] = 0.f;
        }
    }
    __syncthreads();

    // ---- Phase C2: layer1 fp16 MFMA per 16-point group, in-place out ----
    for (int g = w; g < NGRP; g += NWAVE) {
        int P = g * 16 + h;
        int rot = (P >> 1) & 3;
        unsigned* bb = &s_f1[P * 16];
        uint4 ur = *(const uint4*)&bb[((kc + rot) & 3) * 4];
        uint4 ui = *(const uint4*)&bb[(((kc ^ 2) + rot) & 3) * 4];
        hf8 br, bi;
        __builtin_memcpy(&br, &ur, 16);
        __builtin_memcpy(&bi, &ui, 16);
        f4 zc = {0.f, 0.f, 0.f, 0.f};
        f4 Dr = __builtin_amdgcn_mfma_f32_16x16x32_f16(a1, br, zc, 0, 0, 0);
        f4 Di = __builtin_amdgcn_mfma_f32_16x16x32_f16(a1, bi, zc, 0, 0, 0);
        if (P < NPTS) {
            float mm = s_m[P];
            Dr *= mm; Di *= mm;          // undo per-point feature scale
            if (!z1) {
#pragma unroll
                for (int r = 0; r < 4; ++r) {
                    float q2 = Dr[r]*Dr[r] + Di[r]*Di[r] + 1e-12f;
                    float sb = fmaxf(fmaf(b1[4*kc + r], __frsqrt_rn(q2), 1.f), 0.f);
                    Dr[r] *= sb; Di[r] *= sb;
                }
            }
            // lane holds out ch 4kc..4kc+3 of point P -> r dwords 2kc,2kc+1
            unsigned pr0 = cvt_pk_bf16(Dr[0], Dr[1]);
            unsigned pr1 = cvt_pk_bf16(Dr[2], Dr[3]);
            unsigned pi0 = cvt_pk_bf16(Di[0], Di[1]);
            unsigned pi1 = cvt_pk_bf16(Di[2], Di[3]);
            int base = P * 16 + ((kc & 1) << 1);
            int ar = base + ((((kc >> 1) + rot) & 3) << 2);
            int ai = base + ((((kc >> 1) + 2 + rot) & 3) << 2);
            *(uint2*)&s_f1[ar] = make_uint2(pr0, pr1);
            *(uint2*)&s_f1[ai] = make_uint2(pi0, pi1);
        }
    }
    __syncthreads();

    // ---- Phase D: layer2 via tap-paired MFMA + readout (bf16) ----
    float4 ro_lo = *(const float4*)ro;
    float4 ro_hi = *(const float4*)(ro + 4);
    float4 b2_lo = *(const float4*)b2;
    float4 b2_hi = *(const float4*)(b2 + 4);
    float4 zf4 = make_float4(0.f, 0.f, 0.f, 0.f);
    float4 rv = (kc == 0) ? ro_lo : ((kc == 1) ? ro_hi : zf4);
    float4 bv = (kc == 0) ? b2_lo : ((kc == 1) ? b2_hi : zf4);
    float rob0 = rob[0];

    // per-pair per-lane B tap offset (row-invariant; depends on half only)
    int dpl[3];
    dpl[0] = half ? REG : 0;
    dpl[1] = half ? 1 : -REG;
    dpl[2] = -1;

#pragma unroll
    for (int g = 0; g < RPW; ++g) {
        int row = w * RPW + g;
        int posc = (row + 1) * REG + (h + 1);
        int lb2 = (row + 3) * LKR + (h + 3);
        f2 lx = s_ux[lb2], ly = s_uy[lb2];
        f2 mx = s_ux[lb2 - LKR], my = s_uy[lb2 - 1];

        float Lr[3], Li[3];
        Lr[0] = half ? lx.x : 1.f;   Li[0] = half ? lx.y : 0.f;
        Lr[1] = half ? ly.x : mx.x;  Li[1] = half ? ly.y : -mx.y;
        Lr[2] = half ? 0.f : my.x;   Li[2] = half ? 0.f : -my.y;

        f2 a2r01 = {0.f, 0.f}, a2r23 = {0.f, 0.f};
        f2 a2i01 = {0.f, 0.f}, a2i23 = {0.f, 0.f};
#pragma unroll
        for (int pq = 0; pq < 3; ++pq) {
            int posc2 = posc + dpl[pq];
            int rot2 = (posc2 >> 1) & 3;
            int bbb = posc2 * 16;
            uint4 ur = *(const uint4*)&s_f1[bbb + ((((kc & 1) + rot2) & 3) << 2)];
            uint4 ui = *(const uint4*)&s_f1[bbb + ((((kc & 1) + 2 + rot2) & 3) << 2)];
            bf8 br, bi;
            __builtin_memcpy(&br, &ur, 16);
            __builtin_memcpy(&bi, &ui, 16);
            f4 zc = {0.f, 0.f, 0.f, 0.f};
            f4 sr = __builtin_amdgcn_mfma_f32_16x16x32_bf16(afr[pq], br, zc, 0, 0, 0);
            f4 si = __builtin_amdgcn_mfma_f32_16x16x32_bf16(afr[pq], bi, zc, 0, 0, 0);
            f2 sr01 = {sr[0], sr[1]}, sr23 = {sr[2], sr[3]};
            f2 si01 = {si[0], si[1]}, si23 = {si[2], si[3]};
            // a2r += Lr*sr - Li*si ; a2i += Lr*si + Li*sr
            a2r01 += Lr[pq] * sr01 - Li[pq] * si01;
            a2r23 += Lr[pq] * sr23 - Li[pq] * si23;
            a2i01 += Lr[pq] * si01 + Li[pq] * sr01;
            a2i23 += Lr[pq] * si23 + Li[pq] * sr23;
        }

        // fold highK-half rows (8-15, in quads 2/3) into lowK rows (quads 0/1)
        float ar_[4], ai_[4];
        ar_[0] = a2r01.x; ar_[1] = a2r01.y; ar_[2] = a2r23.x; ar_[3] = a2r23.y;
        ai_[0] = a2i01.x; ai_[1] = a2i01.y; ai_[2] = a2i23.x; ai_[3] = a2i23.y;
#pragma unroll
        for (int c = 0; c < 4; ++c) {
            ar_[c] += __shfl_xor(ar_[c], 32, 64);
            ai_[c] += __shfl_xor(ai_[c], 32, 64);
        }

        float q4[4];
#pragma unroll
        for (int c = 0; c < 4; ++c)
            q4[c] = ar_[c] * ar_[c] + ai_[c] * ai_[c];
        float res;
        if (z2) {
            res = rv.x * q4[0] + rv.y * q4[1] + rv.z * q4[2] + rv.w * q4[3];
        } else {
            float bvv[4] = {bv.x, bv.y, bv.z, bv.w};
            float rvv[4] = {rv.x, rv.y, rv.z, rv.w};
            res = 0.f;
#pragma unroll
            for (int r = 0; r < 4; ++r) {
                float qq = q4[r];
                float sb = fmaxf(fmaf(bvv[r], __frsqrt_rn(qq + 1e-12f), 1.f), 0.f);
                res = fmaf(rvv[r], sb * sb * qq, res);
            }
        }
        res += __shfl_xor(res, 16, 64);
        if (kc == 0)
            out[(size_t)b * LL + (size_t)(i0 + row) * LQ + (j0 + h)] = res + rob0;
    }
}

// ---------------------------------------------------------------------------
extern "C" void kernel_launch(void* const* d_in, const int* in_sizes, int n_in,
                              void* d_out, int out_size, void* d_ws, size_t ws_size,
                              hipStream_t stream) {
    const float* x   = (const float*)d_in[0];
    const float* c1  = (const float*)d_in[1];
    const float* fw1 = (const float*)d_in[2];
    const float* bw1 = (const float*)d_in[3];
    const float* b1  = (const float*)d_in[4];
    const float* c2  = (const float*)d_in[5];
    const float* fw2 = (const float*)d_in[6];
    const float* bw2 = (const float*)d_in[7];
    const float* b2  = (const float*)d_in[8];
    const float* ro  = (const float*)d_in[9];
    const float* rob = (const float*)d_in[10];
    float* out = (float*)d_out;
    float* ws  = (float*)d_ws;

    k_scan<<<BQ * 8 + 1, 256, 0, stream>>>(x, c1, fw1, bw1, c2, fw2, bw2, ws);
    dim3 grid(LQ / TILE, LQ / TILE, BQ);
    k_main<<<grid, NTHR, 0, stream>>>(x, b1, b2, ro, rob, ws, out);
}

// Round 11
// 122.975 us; speedup vs baseline: 1.0054x; 1.0043x over previous
//
#include <hip/hip_runtime.h>
#include <math.h>

// B=64, L=128, H=16, O=8
#define LQ   128
#define BQ   64
#define LL   (LQ*LQ)
#define H1   16
#define O2   8
#define TILE 16
#define NTHR 512
#define NWAVE 8
#define RPW  2           // output rows per wave in Phase D
#define REG  18          // f1 region (origin i0-1)
#define NPTS (REG*REG)   // 324
#define NPTS_PAD 336     // 21 groups * 16
#define NGRP 21
#define PCR  22          // pc region (origin i0-3)
#define PCN  (PCR*PCR)   // 484
#define LKR  23          // link region (origin i0-3)
#define LKN  (LKR*LKR)   // 529

typedef float f2 __attribute__((ext_vector_type(2)));
using bf8 = __attribute__((ext_vector_type(8))) short;     // 8 bf16 (4 VGPR)
using hf8 = __attribute__((ext_vector_type(8))) _Float16;  // 8 fp16 (4 VGPR)
using f4  = __attribute__((ext_vector_type(4))) float;     // MFMA C/D

__device__ __forceinline__ int wrapi(int v) { return v & (LQ - 1); }

// RNE pack: low16 = bf16(lo), high16 = bf16(hi)
__device__ __forceinline__ unsigned cvt_pk_bf16(float lo, float hi) {
    unsigned r;
    asm("v_cvt_pk_bf16_f32 %0, %1, %2" : "=v"(r) : "v"(lo), "v"(hi));
    return r;
}
// RTZ pack: low16 = fp16(lo), high16 = fp16(hi)
__device__ __forceinline__ unsigned cvt_pk_f16(float lo, float hi) {
    auto h2 = __builtin_amdgcn_cvt_pkrtz(lo, hi);
    unsigned r;
    __builtin_memcpy(&r, &h2, 4);
    return r;
}

// ws layout:
//   float2[0 .. BQ*LL)                     seed (8 MB)
//   uint4 [0 .. 256) at float ofs 2*BQ*LL  pre-packed MFMA A-fragments:
//     [0..64)    layer-1 W fragment per lane, fp16 (K15-31 zero)
//     [64..256)  layer-2 W fragments, 3 pairs x 64 lanes, bf16 RNE
#define WS_WF ((size_t)2 * BQ * LL)

// ---------------------------------------------------------------------------
__global__ __launch_bounds__(256)
void k_scan(const float* __restrict__ x,
            const float* __restrict__ c1, const float* __restrict__ fw1,
            const float* __restrict__ bw1,
            const float* __restrict__ c2, const float* __restrict__ fw2,
            const float* __restrict__ bw2, float* __restrict__ ws) {
    int blk = blockIdx.x;
    if (blk == BQ * 8) {
        int tid = threadIdx.x;
        uint4* wf = (uint4*)(ws + WS_WF);
        if (tid < 64) {
            // layer-1 A fragment (fp16): A[h][k], k=3q+c for k<15, else 0
            int kc = tid >> 4, h = tid & 15;
            unsigned dw[4];
            float v[8];
#pragma unroll
            for (int j = 0; j < 8; ++j) {
                int k = kc * 8 + j;
                float val = 0.f;
                if (k < 15) {
                    int q = k / 3, c = k - q * 3;
                    const float* src = (q == 0) ? c1 : (q == 1) ? fw1
                                     : (q == 2) ? bw1 : (q == 3) ? (fw1 + 48)
                                     : (bw1 + 48);
                    val = src[h * 3 + c];
                }
                v[j] = val;
            }
#pragma unroll
            for (int d = 0; d < 4; ++d) dw[d] = cvt_pk_f16(v[2*d], v[2*d+1]);
            uint4 u = {dw[0], dw[1], dw[2], dw[3]};
            wf[tid] = u;
        } else {
            // layer-2 A fragments (3 tap-pairs), per-lane as in Phase D (RNE)
            int idx = tid - 64;
            int pq = idx >> 6, lane = idx & 63;
            int kc = lane >> 4, h = lane & 15, half = kc >> 1;
            const float* wsrc = half
                ? ((pq == 0) ? fw2 : (pq == 1) ? (fw2 + O2 * H1) : (const float*)0)
                : ((pq == 0) ? c2  : (pq == 1) ? bw2 : (bw2 + O2 * H1));
            unsigned dw[4] = {0u, 0u, 0u, 0u};
            int wrow = half ? (h - 8) : h;
            bool valid = half ? (h >= 8 && wsrc != 0) : (h < 8);
            if (valid) {
                const float* wp2 = wsrc + wrow * H1 + (kc & 1) * 8;
#pragma unroll
                for (int d = 0; d < 4; ++d)
                    dw[d] = cvt_pk_bf16(wp2[2*d], wp2[2*d+1]);
            }
            uint4 u = {dw[0], dw[1], dw[2], dw[3]};
            wf[64 + idx] = u;
        }
        return;
    }
    int b = blk >> 3, rq = blk & 7;
    int l = threadIdx.x & 63, w = threadIdx.x >> 6;
    const float* x0 = x + (size_t)b * 4 * LL;
    const float* x1 = x0 + LL;

    float ur0 = x0[(2 * l) * LQ],     ui0 = x1[(2 * l) * LQ];
    float ur1 = x0[(2 * l + 1) * LQ], ui1 = x1[(2 * l + 1) * LQ];
    float pr = ur0 * ur1 - ui0 * ui1;
    float pi = ur0 * ui1 + ui0 * ur1;
    for (int d = 1; d < 64; d <<= 1) {
        float qr = __shfl_up(pr, d, 64);
        float qi = __shfl_up(pi, d, 64);
        if (l >= d) {
            float nr = qr * pr - qi * pi;
            float ni = qr * pi + qi * pr;
            pr = nr; pi = ni;
        }
    }
    float er = __shfl_up(pr, 1, 64);
    float ei = __shfl_up(pi, 1, 64);
    if (l == 0) { er = 1.f; ei = 0.f; }
    float e1r = er * ur0 - ei * ui0;
    float e1i = er * ui0 + ei * ur0;

    const float* yrp = x + (size_t)(b * 4 + 2) * LL;
    const float* yip = yrp + LL;
    float4* seed4 = (float4*)ws;

    for (int k = 0; k < 4; ++k) {
        int i = rq * 16 + w * 4 + k;
        float cxr = __shfl((i & 1) ? e1r : er, i >> 1, 64);
        float cxi = __shfl((i & 1) ? e1i : ei, i >> 1, 64);
        const float* yr = yrp + (size_t)i * LQ;
        const float* yi = yip + (size_t)i * LQ;
        float vr0 = yr[2 * l],     vi0 = yi[2 * l];
        float vr1 = yr[2 * l + 1], vi1 = yi[2 * l + 1];
        float sr = vr0 * vr1 - vi0 * vi1;
        float si = vr0 * vi1 + vi0 * vr1;
        for (int d = 1; d < 64; d <<= 1) {
            float qr = __shfl_up(sr, d, 64);
            float qi = __shfl_up(si, d, 64);
            if (l >= d) {
                float nr = qr * sr - qi * si;
                float ni = qr * si + qi * sr;
                sr = nr; si = ni;
            }
        }
        float gr = __shfl_up(sr, 1, 64);
        float gi = __shfl_up(si, 1, 64);
        if (l == 0) { gr = 1.f; gi = 0.f; }
        float s0r = cxr * gr - cxi * gi;
        float s0i = cxr * gi + cxi * gr;
        float s1r = s0r * vr0 - s0i * vi0;
        float s1i = s0r * vi0 + s0i * vr0;
        seed4[((size_t)b * LL + (size_t)i * LQ) / 2 + l] =
            make_float4(s0r, -s0i, s1r, -s1i);
    }
}

// ---------------------------------------------------------------------------
// s_f1 layout: per point P, 16 dwords in four 4-dword slots rotated by
// rot = (P>>1)&3:  dword(slot s, d) at 16*P + ((s+rot)&3)*4 + d.
// Feature phase (fp16, scaled by s=rcp(m), m=max|tap| in s_m[P]):
//   s0/1 = Fr d0-3/4-7 (K0-15, K15 pad), s2/3 = Fi.  A rows K15-31 are zero,
//   so kc>=2 lanes read the other plane as a finite dummy (exact 0 contrib).
// Output phase (C2 write, D read; bf16): s0/1 = out_r ch0-7/8-15, s2/3 = out_i.
__global__ __launch_bounds__(NTHR, 8)
void k_main(const float* __restrict__ x,
            const float* __restrict__ b1, const float* __restrict__ b2,
            const float* __restrict__ ro, const float* __restrict__ rob,
            const float* __restrict__ ws, float* __restrict__ out) {
    __shared__ __align__(16) unsigned s_f1[NPTS_PAD * 16];   // 21504 B
    __shared__ f2 s_ux[LKN];                 // 4232 B
    __shared__ f2 s_uy[LKN];                 // 4232 B
    __shared__ float s_pc[PCN];              // 1936 B
    __shared__ float s_m[NPTS_PAD];          // 1344 B (total 33248 -> 4 blk/CU)
    int tid = threadIdx.x;
    int b = blockIdx.z, i0 = blockIdx.y * TILE, j0 = blockIdx.x * TILE;
    const float* x0 = x + (size_t)b * 4 * LL;
    const float* x1 = x0 + LL;
    const float* x2 = x0 + 2 * LL;
    const float* x3 = x0 + 3 * LL;
    const float2* seed = (const float2*)ws + (size_t)b * LL;
    const uint4* wf = (const uint4*)(ws + WS_WF);

    int lane = tid & 63, w = tid >> 6;
    int kc = lane >> 4, h = lane & 15, half = kc >> 1;

    // uniform zero-bias fast-path flags (exact: scale==1.0 when bias==0)
    bool z1 = true;
#pragma unroll
    for (int hh = 0; hh < H1; ++hh) z1 = z1 && (b1[hh] == 0.f);
    bool z2 = true;
#pragma unroll
    for (int oo = 0; oo < O2; ++oo) z2 = z2 && (b2[oo] == 0.f);

    // pre-packed A fragments (global, L2-hot: 4 KB shared by all blocks)
    hf8 a1;
    { uint4 u = wf[lane]; __builtin_memcpy(&a1, &u, 16); }
    bf8 afr[3];
#pragma unroll
    for (int pq = 0; pq < 3; ++pq) {
        uint4 u = wf[64 + pq * 64 + lane];
        __builtin_memcpy(&afr[pq], &u, 16);
    }

    // ---- Phase A: stage links (23x23, origin -3); seed stays in global ----
    for (int p = tid; p < LKN; p += NTHR) {
        int ri = p / LKR, rj = p - ri * LKR;
        int gi = wrapi(i0 - 3 + ri), gj = wrapi(j0 - 3 + rj);
        int idx = gi * LQ + gj;
        s_ux[p] = (f2){x0[idx], x1[idx]};
        s_uy[p] = (f2){x2[idx], x3[idx]};
    }
    __syncthreads();

    // ---- Phase B: pc on 22x22 (origin -3) via complex plaquette product ----
    for (int p = tid; p < PCN; p += NTHR) {
        int ri = p / PCR, rj = p - ri * PCR;
        int lb = ri * LKR + rj;
        f2 u1 = s_ux[lb];
        f2 u2 = s_uy[lb + LKR];
        f2 u3 = s_ux[lb + 1];
        f2 u4 = s_uy[lb];
        float ar = u1.x * u2.x - u1.y * u2.y, ai = u1.x * u2.y + u1.y * u2.x;
        float br = ar * u3.x + ai * u3.y,     bi = -ar * u3.y + ai * u3.x;
        float zr = br * u4.x + bi * u4.y,     zi = -br * u4.y + bi * u4.x;
        s_pc[p] = zr * __frsqrt_rn(fmaf(zr, zr, zi * zi) + 1e-30f);
    }
    __syncthreads();

    // ---- Phase C1: per-point 15-feature vector -> scaled fp16 -> s_f1 ----
    for (int p = tid; p < NPTS_PAD; p += NTHR) {
        int rot = (p >> 1) & 3;
        unsigned* dst = &s_f1[p * 16];
        if (p < NPTS) {
            int ri = p / REG, rj = p - ri * REG;
            int lb = (ri + 2) * LKR + (rj + 2);
            int cb = (ri + 2) * PCR + (rj + 2);

            // seed taps from global (f1 point = global (i0-1+ri, j0-1+rj))
            int gi0 = wrapi(i0 - 1 + ri), gim = wrapi(i0 - 2 + ri), gip = wrapi(i0 + ri);
            int gj0 = wrapi(j0 - 1 + rj), gjm = wrapi(j0 - 2 + rj), gjp = wrapi(j0 + rj);
            float2 SC  = seed[gi0 * LQ + gj0];
            float2 SXP = seed[gip * LQ + gj0];
            float2 SXM = seed[gim * LQ + gj0];
            float2 SYP = seed[gi0 * LQ + gjp];
            float2 SYM = seed[gi0 * LQ + gjm];

            f2 lx = s_ux[lb], ly = s_uy[lb];
            f2 mx = s_ux[lb - LKR], my = s_uy[lb - 1];
            float tr[5], ti[5], tc[5], tv[5];
            tr[0] = SC.x;                          ti[0] = SC.y;
            tr[1] = lx.x * SXP.x - lx.y * SXP.y;   ti[1] = lx.x * SXP.y + lx.y * SXP.x;
            tr[2] = mx.x * SXM.x + mx.y * SXM.y;   ti[2] = mx.x * SXM.y - mx.y * SXM.x;
            tr[3] = ly.x * SYP.x - ly.y * SYP.y;   ti[3] = ly.x * SYP.y + ly.y * SYP.x;
            tr[4] = my.x * SYM.x + my.y * SYM.y;   ti[4] = my.x * SYM.y - my.y * SYM.x;

            // 13-point pc diamond
            float p00 = s_pc[cb];
            float pP0 = s_pc[cb + PCR],     pM0 = s_pc[cb - PCR];
            float p0P = s_pc[cb + 1],       p0M = s_pc[cb - 1];
            float pP20 = s_pc[cb + 2*PCR],  pM20 = s_pc[cb - 2*PCR];
            float p0P2 = s_pc[cb + 2],      p0M2 = s_pc[cb - 2];
            float pPP = s_pc[cb + PCR + 1], pPM = s_pc[cb + PCR - 1];
            float pMP = s_pc[cb - PCR + 1], pMM = s_pc[cb - PCR - 1];
            tc[0] = p00; tc[1] = pP0; tc[2] = pM0; tc[3] = p0P; tc[4] = p0M;
            tv[0] = (p00 + pP0 + pM0 + p0P + p0M) * 0.2f;
            tv[1] = (pP0 + pP20 + p00 + pPP + pPM) * 0.2f;
            tv[2] = (pM0 + p00 + pM20 + pMP + pMM) * 0.2f;
            tv[3] = (p0P + pPP + pMP + p0P2 + p00) * 0.2f;
            tv[4] = (p0M + pPM + pMM + p00 + p0M2) * 0.2f;

            // per-point scale: |F| <= m = max|tap| (|pc|,|pavg| <= 1)
            float m = 1e-30f;
#pragma unroll
            for (int q = 0; q < 5; ++q)
                m = fmaxf(m, fmaxf(fabsf(tr[q]), fabsf(ti[q])));
            float s = __frcp_rn(m);

            float Fr[16], Fi[16];
#pragma unroll
            for (int q = 0; q < 5; ++q) {
                float trq = tr[q] * s, tiq = ti[q] * s;
                Fr[3*q]   = trq;          Fi[3*q]   = tiq;
                Fr[3*q+1] = tc[q]*trq;    Fi[3*q+1] = tc[q]*tiq;
                Fr[3*q+2] = tv[q]*trq;    Fi[3*q+2] = tv[q]*tiq;
            }
            Fr[15] = 0.f; Fi[15] = 0.f;
            unsigned hr[8], hi_[8];
#pragma unroll
            for (int d = 0; d < 8; ++d) {
                hr[d]  = cvt_pk_f16(Fr[2*d], Fr[2*d+1]);
                hi_[d] = cvt_pk_f16(Fi[2*d], Fi[2*d+1]);
            }
            uint4 vs0 = {hr[0], hr[1], hr[2], hr[3]};
            uint4 vs1 = {hr[4], hr[5], hr[6], hr[7]};
            uint4 vs2 = {hi_[0], hi_[1], hi_[2], hi_[3]};
            uint4 vs3 = {hi_[4], hi_[5], hi_[6], hi_[7]};
            *(uint4*)&dst[((0 + rot) & 3) * 4] = vs0;
            *(uint4*)&dst[((1 + rot) & 3) * 4] = vs1;
            *(uint4*)&dst[((2 + rot) & 3) * 4] = vs2;
            *(uint4*)&dst[((3 + rot) & 3) * 4] = vs3;
            s_m[p] = m;
        } else {
            uint4 z = {0u, 0u, 0u, 0u};
#pragma unroll
            for (int sl = 0; sl < 4; ++sl) *(uint4*)&dst[sl * 4] = z;
            s_m[p] = 0.f;
        }
    }
    __syncthreads();

    // ---- Phase C2: layer1 fp16 MFMA per 16-point group, in-place out ----
    for (int g = w; g < NGRP; g += NWAVE) {
        int P = g * 16 + h;
        int rot = (P >> 1) & 3;
        unsigned* bb = &s_f1[P * 16];
        uint4 ur = *(const uint4*)&bb[((kc + rot) & 3) * 4];
        uint4 ui = *(const uint4*)&bb[(((kc ^ 2) + rot) & 3) * 4];
        hf8 br, bi;
        __builtin_memcpy(&br, &ur, 16);
        __builtin_memcpy(&bi, &ui, 16);
        f4 zc = {0.f, 0.f, 0.f, 0.f};
        f4 Dr = __builtin_amdgcn_mfma_f32_16x16x32_f16(a1, br, zc, 0, 0, 0);
        f4 Di = __builtin_amdgcn_mfma_f32_16x16x32_f16(a1, bi, zc, 0, 0, 0);
        if (P < NPTS) {
            float mm = s_m[P];
            Dr *= mm; Di *= mm;          // undo per-point feature scale
            if (!z1) {
#pragma unroll
                for (int r = 0; r < 4; ++r) {
                    float q2 = Dr[r]*Dr[r] + Di[r]*Di[r] + 1e-12f;
                    float sb = fmaxf(fmaf(b1[4*kc + r], __frsqrt_rn(q2), 1.f), 0.f);
                    Dr[r] *= sb; Di[r] *= sb;
                }
            }
            // lane holds out ch 4kc..4kc+3 of point P -> r dwords 2kc,2kc+1
            unsigned pr0 = cvt_pk_bf16(Dr[0], Dr[1]);
            unsigned pr1 = cvt_pk_bf16(Dr[2], Dr[3]);
            unsigned pi0 = cvt_pk_bf16(Di[0], Di[1]);
            unsigned pi1 = cvt_pk_bf16(Di[2], Di[3]);
            int base = P * 16 + ((kc & 1) << 1);
            int ar = base + ((((kc >> 1) + rot) & 3) << 2);
            int ai = base + ((((kc >> 1) + 2 + rot) & 3) << 2);
            *(uint2*)&s_f1[ar] = make_uint2(pr0, pr1);
            *(uint2*)&s_f1[ai] = make_uint2(pi0, pi1);
        }
    }
    __syncthreads();

    // ---- Phase D: layer2 via tap-paired MFMA + readout (bf16) ----
    // Rotation accumulation via packed f2 FMA (v_pk_fma_f32 target).
    float4 ro_lo = *(const float4*)ro;
    float4 ro_hi = *(const float4*)(ro + 4);
    float4 b2_lo = *(const float4*)b2;
    float4 b2_hi = *(const float4*)(b2 + 4);
    float4 zf4 = make_float4(0.f, 0.f, 0.f, 0.f);
    float4 rv = (kc == 0) ? ro_lo : ((kc == 1) ? ro_hi : zf4);
    float4 bv = (kc == 0) ? b2_lo : ((kc == 1) ? b2_hi : zf4);
    float rob0 = rob[0];

    // per-pair per-lane B tap offset (row-invariant; depends on half only)
    int dpl[3];
    dpl[0] = half ? REG : 0;
    dpl[1] = half ? 1 : -REG;
    dpl[2] = -1;

#pragma unroll
    for (int g = 0; g < RPW; ++g) {
        int row = w * RPW + g;
        int posc = (row + 1) * REG + (h + 1);
        int lb2 = (row + 3) * LKR + (h + 3);
        f2 lx = s_ux[lb2], ly = s_uy[lb2];
        f2 mx = s_ux[lb2 - LKR], my = s_uy[lb2 - 1];

        float Lr[3], Li[3];
        Lr[0] = half ? lx.x : 1.f;   Li[0] = half ? lx.y : 0.f;
        Lr[1] = half ? ly.x : mx.x;  Li[1] = half ? ly.y : -mx.y;
        Lr[2] = half ? 0.f : my.x;   Li[2] = half ? 0.f : -my.y;

        f2 a2r01 = {0.f, 0.f}, a2r23 = {0.f, 0.f};
        f2 a2i01 = {0.f, 0.f}, a2i23 = {0.f, 0.f};
#pragma unroll
        for (int pq = 0; pq < 3; ++pq) {
            int posc2 = posc + dpl[pq];
            int rot2 = (posc2 >> 1) & 3;
            int bbb = posc2 * 16;
            uint4 ur = *(const uint4*)&s_f1[bbb + ((((kc & 1) + rot2) & 3) << 2)];
            uint4 ui = *(const uint4*)&s_f1[bbb + ((((kc & 1) + 2 + rot2) & 3) << 2)];
            bf8 br, bi;
            __builtin_memcpy(&br, &ur, 16);
            __builtin_memcpy(&bi, &ui, 16);
            f4 zc = {0.f, 0.f, 0.f, 0.f};
            f4 sr = __builtin_amdgcn_mfma_f32_16x16x32_bf16(afr[pq], br, zc, 0, 0, 0);
            f4 si = __builtin_amdgcn_mfma_f32_16x16x32_bf16(afr[pq], bi, zc, 0, 0, 0);
            f2 sr01 = {sr[0], sr[1]}, sr23 = {sr[2], sr[3]};
            f2 si01 = {si[0], si[1]}, si23 = {si[2], si[3]};
            // a2r += Lr*sr - Li*si ; a2i += Lr*si + Li*sr
            // explicit splat + vector fma -> v_pk_fma_f32 (2 FLOP/inst)
            f2 Lrv  = {Lr[pq], Lr[pq]};
            f2 Liv  = {Li[pq], Li[pq]};
            f2 nLiv = {-Li[pq], -Li[pq]};
            a2r01 = __builtin_elementwise_fma(Lrv,  sr01, a2r01);
            a2r01 = __builtin_elementwise_fma(nLiv, si01, a2r01);
            a2r23 = __builtin_elementwise_fma(Lrv,  sr23, a2r23);
            a2r23 = __builtin_elementwise_fma(nLiv, si23, a2r23);
            a2i01 = __builtin_elementwise_fma(Lrv,  si01, a2i01);
            a2i01 = __builtin_elementwise_fma(Liv,  sr01, a2i01);
            a2i23 = __builtin_elementwise_fma(Lrv,  si23, a2i23);
            a2i23 = __builtin_elementwise_fma(Liv,  sr23, a2i23);
        }

        // fold highK-half rows (8-15, in quads 2/3) into lowK rows (quads 0/1)
        float ar_[4], ai_[4];
        ar_[0] = a2r01.x; ar_[1] = a2r01.y; ar_[2] = a2r23.x; ar_[3] = a2r23.y;
        ai_[0] = a2i01.x; ai_[1] = a2i01.y; ai_[2] = a2i23.x; ai_[3] = a2i23.y;
#pragma unroll
        for (int c = 0; c < 4; ++c) {
            ar_[c] += __shfl_xor(ar_[c], 32, 64);
            ai_[c] += __shfl_xor(ai_[c], 32, 64);
        }

        // packed magnitude: q = ar*ar + ai*ai  (v_pk_mul + v_pk_fma)
        f2 arp01 = {ar_[0], ar_[1]}, arp23 = {ar_[2], ar_[3]};
        f2 aip01 = {ai_[0], ai_[1]}, aip23 = {ai_[2], ai_[3]};
        f2 q01 = __builtin_elementwise_fma(arp01, arp01, aip01 * aip01);
        f2 q23 = __builtin_elementwise_fma(arp23, arp23, aip23 * aip23);
        float q4[4] = {q01.x, q01.y, q23.x, q23.y};
        float res;
        if (z2) {
            res = rv.x * q4[0] + rv.y * q4[1] + rv.z * q4[2] + rv.w * q4[3];
        } else {
            float bvv[4] = {bv.x, bv.y, bv.z, bv.w};
            float rvv[4] = {rv.x, rv.y, rv.z, rv.w};
            res = 0.f;
#pragma unroll
            for (int r = 0; r < 4; ++r) {
                float qq = q4[r];
                float sb = fmaxf(fmaf(bvv[r], __frsqrt_rn(qq + 1e-12f), 1.f), 0.f);
                res = fmaf(rvv[r], sb * sb * qq, res);
            }
        }
        res += __shfl_xor(res, 16, 64);
        if (kc == 0)
            out[(size_t)b * LL + (size_t)(i0 + row) * LQ + (j0 + h)] = res + rob0;
    }
}

// ---------------------------------------------------------------------------
extern "C" void kernel_launch(void* const* d_in, const int* in_sizes, int n_in,
                              void* d_out, int out_size, void* d_ws, size_t ws_size,
                              hipStream_t stream) {
    const float* x   = (const float*)d_in[0];
    const float* c1  = (const float*)d_in[1];
    const float* fw1 = (const float*)d_in[2];
    const float* bw1 = (const float*)d_in[3];
    const float* b1  = (const float*)d_in[4];
    const float* c2  = (const float*)d_in[5];
    const float* fw2 = (const float*)d_in[6];
    const float* bw2 = (const float*)d_in[7];
    const float* b2  = (const float*)d_in[8];
    const float* ro  = (const float*)d_in[9];
    const float* rob = (const float*)d_in[10];
    float* out = (float*)d_out;
    float* ws  = (float*)d_ws;

    k_scan<<<BQ * 8 + 1, 256, 0, stream>>>(x, c1, fw1, bw1, c2, fw2, bw2, ws);
    dim3 grid(LQ / TILE, LQ / TILE, BQ);
    k_main<<<grid, NTHR, 0, stream>>>(x, b1, b2, ro, rob, ws, out);
}